// Round 4
// baseline (1152.473 us; speedup 1.0000x reference)
//
#include <hip/hip_runtime.h>
#include <math.h>

#define BB 32
#define TD 2048
#define TE 1024
#define DIM 256
#define INDIM 80

typedef __attribute__((ext_vector_type(8))) _Float16 f16x8;
typedef __attribute__((ext_vector_type(4))) float f32x4;

__device__ __forceinline__ float sigmoidf_(float x){ return 1.f/(1.f+__expf(-x)); }

__device__ __forceinline__ unsigned pack2h(float a, float b){
  union { _Float16 h[2]; unsigned u; } x;
  x.h[0] = (_Float16)a; x.h[1] = (_Float16)b;
  return x.u;
}

// ------- conv weight reorder: w(512,256,5) f32 -> Wf[o][tap*256+ic] fp16 -------
__global__ __launch_bounds__(256) void k_wprep(const float* __restrict__ w,
    _Float16* __restrict__ Wf)
{
  int i = blockIdx.x*256 + threadIdx.x;   // 512*1280
  int o = i / 1280;
  int kk = i - o*1280;
  int tap = kk >> 8, ic = kk & 255;
  Wf[i] = (_Float16)w[(size_t)o*1280 + ic*5 + tap];
}

// ------- Wq 2-term fp16 split (row-major 256x256) -------
__global__ __launch_bounds__(256) void k_qwprep(const float* __restrict__ W,
    _Float16* __restrict__ Wh, _Float16* __restrict__ Wl)
{
  int i = blockIdx.x*256 + threadIdx.x;   // 65536
  float f = W[i];
  _Float16 h = (_Float16)f;
  Wh[i] = h;
  Wl[i] = (_Float16)(f - (float)h);
}

// ------- W_lin 2-term fp16 split, padded: (256,80) -> [256][96] -------
__global__ __launch_bounds__(256) void k_lwprep(const float* __restrict__ W,
    _Float16* __restrict__ Wh, _Float16* __restrict__ Wl)
{
  int i = blockIdx.x*256 + threadIdx.x;   // 256*96
  int d = i / 96, k = i - d*96;
  float f = (k < INDIM) ? W[d*INDIM + k] : 0.f;
  _Float16 h = (_Float16)f;
  Wh[i] = h;
  Wl[i] = (_Float16)(f - (float)h);
}

// ------- W_proj 2-term fp16 split (row-major 80x256) -------
__global__ __launch_bounds__(256) void k_pwprep(const float* __restrict__ W,
    _Float16* __restrict__ Wh, _Float16* __restrict__ Wl)
{
  int i = blockIdx.x*256 + threadIdx.x;   // 80*256
  float f = W[i];
  _Float16 h = (_Float16)f;
  Wh[i] = h;
  Wl[i] = (_Float16)(f - (float)h);
}

// ------- enc prep: Eh = fp16(enc) [b][s][d];  EVt = fp16(enc+emb) transposed [b][d][s] ---
__global__ __launch_bounds__(256) void k_eprep(const float* __restrict__ enc,
    const float* __restrict__ emb, _Float16* __restrict__ Eh,
    _Float16* __restrict__ EVt)
{
  __shared__ float ls[64][65];
  int blk = blockIdx.x;                  // 32 b * 16 st * 4 dt = 2048
  int dt = blk & 3, st = (blk>>2) & 15, b = blk >> 6;
  int s0 = st*64, d0 = dt*64;
  int tid = threadIdx.x;
  for (int k=0;k<16;k++){
    int idx = k*256 + tid;
    int r = idx >> 6, c = idx & 63;
    size_t gi = ((size_t)b*TE + s0 + r)*DIM + d0 + c;
    float e = enc[gi];
    ls[r][c] = e + emb[gi];
    Eh[gi] = (_Float16)e;
  }
  __syncthreads();
  for (int k=0;k<16;k++){
    int idx = k*256 + tid;
    int r = idx >> 6, c = idx & 63;
    EVt[((size_t)b*DIM + d0 + r)*TE + s0 + c] = (_Float16)ls[c][r];
  }
}

// ---------- input linear + shift-right as fp16 MFMA: X = shift(mel) @ W_lin^T ----------
__global__ __launch_bounds__(256) void k_lin_mfma(const float* __restrict__ mel,
    const _Float16* __restrict__ Wh, const _Float16* __restrict__ Wl,
    const float* __restrict__ bias, _Float16* __restrict__ X)
{
  __shared__ __align__(16) _Float16 ms[64*104];   // 64 rows x 96 cols (pad 104)
  int blk = blockIdx.x;                 // 1024: 32 b x 32 t-tiles
  int b = blk >> 5;
  int t0 = (blk & 31) << 6;
  int tid = threadIdx.x;

  for (int i = tid; i < 64*12; i += 256){
    int row = i / 12, cg = (i - row*12) * 8;
    int t = t0 + row - 1;               // shifted: X[t] = lin(mel[t-1])
    f16x8 v = {};
    if (t >= 0 && cg < INDIM){
      const float4* p = (const float4*)(mel + ((size_t)b*TD + t)*INDIM + cg);
      float4 f0 = p[0], f1 = p[1];
      v[0]=(_Float16)f0.x; v[1]=(_Float16)f0.y; v[2]=(_Float16)f0.z; v[3]=(_Float16)f0.w;
      v[4]=(_Float16)f1.x; v[5]=(_Float16)f1.y; v[6]=(_Float16)f1.z; v[7]=(_Float16)f1.w;
    }
    *(f16x8*)&ms[row*104 + cg] = v;
  }
  __syncthreads();

  int wave = tid >> 6, lane = tid & 63;
  int l15 = lane & 15, l4 = lane >> 4;
  int mb = wave << 4;

  f16x8 am[3];
  #pragma unroll
  for (int kc=0;kc<3;kc++) am[kc] = *(f16x8*)&ms[(mb + l15)*104 + kc*32 + l4*8];

  for (int dt=0; dt<16; dt++){
    size_t wrow = (size_t)(dt*16 + l15)*96 + l4*8;
    f32x4 a = (f32x4){0.f,0.f,0.f,0.f};
    #pragma unroll
    for (int kc=0;kc<3;kc++){
      f16x8 bh = *(const f16x8*)(Wh + wrow + kc*32);
      f16x8 bl = *(const f16x8*)(Wl + wrow + kc*32);
      a = __builtin_amdgcn_mfma_f32_16x16x32_f16(am[kc], bh, a, 0,0,0);
      a = __builtin_amdgcn_mfma_f32_16x16x32_f16(am[kc], bl, a, 0,0,0);
    }
    int d = dt*16 + l15;
    float bv = bias[d];
    #pragma unroll
    for (int r=0;r<4;r++){
      int m = mb + l4*4 + r;
      int t = t0 + m;
      X[((size_t)b*TD + t)*DIM + d] = (t==0) ? (_Float16)0.f : (_Float16)(a[r] + bv);
    }
  }
}

// ---------------- conv-GLU as fp16 MFMA GEMM ----------------
template<int TIN_F32, int TOUT_F32>
__global__ __launch_bounds__(256) void k_conv_mfma(const void* __restrict__ Xin_,
    const _Float16* __restrict__ Wf, const float* __restrict__ bias,
    void* __restrict__ Hout_)
{
  __shared__ __align__(16) _Float16 as[68*264];   // 35.9 KB
  int id = blockIdx.x;
  int dtile = id & 3, mtile = id >> 2;
  int b = mtile >> 5;
  int t0 = (mtile & 31) << 6;
  int d0 = dtile << 6;
  int tid = threadIdx.x;

  for (int i = tid; i < 68*32; i += 256){
    int row = i >> 5, cg = (i & 31) << 3;
    int t = t0 - 4 + row;
    f16x8 v = {};
    if (t >= 0){
      if (TIN_F32){
        const float4* p = (const float4*)((const float*)Xin_ + ((size_t)b*TD + t)*DIM + cg);
        float4 f0 = p[0], f1 = p[1];
        v[0]=(_Float16)f0.x; v[1]=(_Float16)f0.y; v[2]=(_Float16)f0.z; v[3]=(_Float16)f0.w;
        v[4]=(_Float16)f1.x; v[5]=(_Float16)f1.y; v[6]=(_Float16)f1.z; v[7]=(_Float16)f1.w;
      } else {
        v = *(const f16x8*)((const _Float16*)Xin_ + ((size_t)b*TD + t)*DIM + cg);
      }
    }
    *(f16x8*)&as[row*264 + cg] = v;
  }
  __syncthreads();

  int lane = tid & 63, wave = tid >> 6;
  int l15 = lane & 15, l4 = lane >> 4;
  int dA = d0 + (wave << 4) + l15;

  const _Float16* pA = Wf + (size_t)dA*1280 + l4*8;
  const _Float16* pG = Wf + (size_t)(256 + dA)*1280 + l4*8;

  f32x4 aca[4], acg[4];
  #pragma unroll
  for (int mt=0;mt<4;mt++){ aca[mt]=(f32x4){0.f,0.f,0.f,0.f}; acg[mt]=(f32x4){0.f,0.f,0.f,0.f}; }

  f16x8 bA = *(const f16x8*)pA;
  f16x8 bG = *(const f16x8*)pG;
  #pragma unroll
  for (int kc = 0; kc < 40; ++kc){
    f16x8 nA = bA, nG = bG;
    if (kc < 39){
      nA = *(const f16x8*)(pA + (kc+1)*32);
      nG = *(const f16x8*)(pG + (kc+1)*32);
    }
    int tap = kc >> 3;
    int ic0 = (kc & 7) << 5;
    int abase = (l15 + tap)*264 + ic0 + l4*8;
    #pragma unroll
    for (int mt=0;mt<4;mt++){
      f16x8 av = *(f16x8*)&as[abase + mt*16*264];
      aca[mt] = __builtin_amdgcn_mfma_f32_16x16x32_f16(av, bA, aca[mt], 0,0,0);
      acg[mt] = __builtin_amdgcn_mfma_f32_16x16x32_f16(av, bG, acg[mt], 0,0,0);
    }
    bA = nA; bG = nG;
  }

  const float is2 = 0.7071067811865476f;
  float ba = bias[dA], bg = bias[256 + dA];
  #pragma unroll
  for (int mt=0; mt<4; mt++){
    #pragma unroll
    for (int r=0;r<4;r++){
      int m = mt*16 + l4*4 + r;
      size_t orow = ((size_t)b*TD + t0 + m)*DIM;
      float xr = TIN_F32 ? ((const float*)Xin_)[orow + dA]
                         : (float)as[(m+4)*264 + dA];
      float a = aca[mt][r] + ba;
      float g = acg[mt][r] + bg;
      float o = (a*sigmoidf_(g) + xr)*is2;
      if (TOUT_F32) ((float*)Hout_)[orow + dA] = o;
      else          ((_Float16*)Hout_)[orow + dA] = (_Float16)o;
    }
  }
}

// ---------- fused q-linear + flash attention + residual ----------
// BARRIER-FREE: swapped-operand QK (mfma(K,Q)) puts score col q at lane l15=q ->
// in-lane softmax (xor16/32 reduce over the 4-lane q-group); P redistributed to
// the PV B-fragment via 16 in-register pull-shuffles (2 per dword: the two
// l4'>>1 reader classes need different pk entries from the same source lane);
// swapped PV (mfma(V^T,P)) keeps alpha/linv at the same lane. K/V fragments read
// directly from L2-resident Eh/EVt (no LDS staging, no vmcnt drains). The only
// LDS is the per-wave-private Q transit (lgkm-ordered). Zero s_barrier.
__global__ __launch_bounds__(256) void k_attn(float* __restrict__ H,
    const _Float16* __restrict__ Wqh, const _Float16* __restrict__ Wql,
    const float* __restrict__ bq,
    const _Float16* __restrict__ Eh, const _Float16* __restrict__ EVt)
{
  __shared__ __align__(16) _Float16 Qt[64*256];   // 32 KB per-wave-private transit

  int i = blockIdx.x;                   // XCD swizzle: same-batch blocks share an XCD
  int b = (i & 7) | ((i >> 8) << 3);
  int t0 = ((i >> 3) & 31) << 6;
  int tid = threadIdx.x;
  int wave = tid >> 6, lane = tid & 63;
  int l15 = lane & 15, l4 = lane >> 4;
  int mb = wave << 4;

  const _Float16* Ehb = Eh + (size_t)b*TE*DIM;
  const _Float16* EVb = EVt + (size_t)b*DIM*TE;

  // ---- q-linear (2-term fp16) ----
  f16x8 ah[8];
  {
    const float* hrow = H + ((size_t)b*TD + t0 + mb + l15)*DIM;
    #pragma unroll
    for (int kc=0;kc<8;kc++){
      const float4* p = (const float4*)(hrow + kc*32 + l4*8);
      float4 f0 = p[0], f1 = p[1];
      f16x8 v;
      v[0]=(_Float16)f0.x; v[1]=(_Float16)f0.y; v[2]=(_Float16)f0.z; v[3]=(_Float16)f0.w;
      v[4]=(_Float16)f1.x; v[5]=(_Float16)f1.y; v[6]=(_Float16)f1.z; v[7]=(_Float16)f1.w;
      ah[kc] = v;
    }
  }

  f32x4 qacc[16];
  for (int ot=0;ot<16;ot++){
    size_t wrow = (size_t)(ot*16 + l15)*256 + l4*8;
    f32x4 a = (f32x4){0.f,0.f,0.f,0.f};
    #pragma unroll
    for (int kc=0;kc<8;kc++){
      f16x8 bh = *(const f16x8*)(Wqh + wrow + kc*32);
      f16x8 bl = *(const f16x8*)(Wql + wrow + kc*32);
      a = __builtin_amdgcn_mfma_f32_16x16x32_f16(ah[kc], bh, a, 0,0,0);
      a = __builtin_amdgcn_mfma_f32_16x16x32_f16(ah[kc], bl, a, 0,0,0);
    }
    qacc[ot] = a;
  }
  #pragma unroll
  for (int ot=0;ot<16;ot++){
    float bqv = bq[ot*16 + l15];
    #pragma unroll
    for (int r=0;r<4;r++) qacc[ot][r] += bqv;
  }

  // ---- Q hi/lo transit through per-wave-private LDS rows (XOR-swizzled, no barriers) ----
  #pragma unroll
  for (int ot=0;ot<16;ot++){
    int o = ot*16 + l15;
    #pragma unroll
    for (int r=0;r<4;r++){
      int row = mb + l4*4 + r;
      Qt[row*256 + (o ^ ((row & 7) << 3))] = (_Float16)qacc[ot][r];
    }
  }
  f16x8 aqh[8];
  {
    int row = mb + l15, sw8 = l15 & 7;
    #pragma unroll
    for (int kc=0;kc<8;kc++)
      aqh[kc] = *(f16x8*)&Qt[row*256 + (((kc*4 + l4) ^ sw8) << 3)];
  }
  #pragma unroll
  for (int ot=0;ot<16;ot++){
    int o = ot*16 + l15;
    #pragma unroll
    for (int r=0;r<4;r++){
      int row = mb + l4*4 + r;
      float v = qacc[ot][r];
      _Float16 h = (_Float16)v;
      Qt[row*256 + (o ^ ((row & 7) << 3))] = (_Float16)(v - (float)h);
    }
  }
  f16x8 aql[8];
  {
    int row = mb + l15, sw8 = l15 & 7;
    #pragma unroll
    for (int kc=0;kc<8;kc++)
      aql[kc] = *(f16x8*)&Qt[row*256 + (((kc*4 + l4) ^ sw8) << 3)];
  }

  // ---- main loop: per-wave independent flash attention over 16 chunks of 64 s ----
  f32x4 oacc[16];                        // (q = l15, d = dt*16 + l4*4 + r)
  #pragma unroll
  for (int dt=0;dt<16;dt++) oacc[dt] = (f32x4){0.f,0.f,0.f,0.f};
  float mrun = -3.0e38f, lrun = 0.f;     // per-lane: q = l15 (replicated over l4)

  for (int c = 0; c < 16; ++c){
    int s0 = c << 6;

    // ---- QK^T swapped: mfma(K, Q) -> sacc: lane l15 = q, s = st*16 + l4*4 + r ----
    f32x4 sacc[4];
    #pragma unroll
    for (int st=0;st<4;st++){
      const _Float16* kr = Ehb + (size_t)(s0 + st*16 + l15)*DIM + l4*8;
      f32x4 a = (f32x4){0.f,0.f,0.f,0.f};
      #pragma unroll
      for (int kc=0;kc<8;kc++){
        f16x8 kf = *(const f16x8*)(kr + kc*32);
        a = __builtin_amdgcn_mfma_f32_16x16x32_f16(kf, aqh[kc], a, 0,0,0);
        a = __builtin_amdgcn_mfma_f32_16x16x32_f16(kf, aql[kc], a, 0,0,0);
      }
      sacc[st] = a;
    }

    // ---- in-lane online softmax (row q = l15; 16 in-lane s + xor16/32 reduce) ----
    float cm = sacc[0][0];
    #pragma unroll
    for (int st=0;st<4;st++)
      #pragma unroll
      for (int r=0;r<4;r++) cm = fmaxf(cm, sacc[st][r]);
    cm = fmaxf(cm, __shfl_xor(cm, 16));
    cm = fmaxf(cm, __shfl_xor(cm, 32));
    float mnew = fmaxf(mrun, cm);
    float alpha = __expf(mrun - mnew);
    mrun = mnew;
    float ps[4][4];
    float lp = 0.f;
    #pragma unroll
    for (int st=0;st<4;st++)
      #pragma unroll
      for (int r=0;r<4;r++){
        float p = __expf(sacc[st][r] - mnew);
        ps[st][r] = p;
        lp += p;
      }
    lrun = lrun*alpha + lp;              // per-lane partial over own l4-group's s

    // ---- pack P to fp16 pairs and redistribute to PV B-fragment layout ----
    // pair index p = kp*16 + l4'*4 + u; source j = (p>>3)*2 + (p&1) =
    // kp*4 + (l4'>>1)*2 + (u&1); source lane l4s = (p>>1)&3 = (l4'*2+(u>>1))&3.
    // Readers of one source lane differ in l4'>>1 -> need BOTH j and j+2:
    // pull both, reader selects by its own l4&2.
    unsigned pk[8];
    #pragma unroll
    for (int st=0;st<4;st++){
      pk[st*2+0] = pack2h(ps[st][0], ps[st][1]);
      pk[st*2+1] = pack2h(ps[st][2], ps[st][3]);
    }
    union { f16x8 v; unsigned u[4]; } pu[2];
    #pragma unroll
    for (int kp=0;kp<2;kp++)
      #pragma unroll
      for (int u=0;u<4;u++){
        int srcl = l15 + (((l4*2 + (u>>1)) & 3) << 4);
        unsigned gA = (unsigned)__shfl((int)pk[kp*4 + (u&1)], srcl);
        unsigned gB = (unsigned)__shfl((int)pk[kp*4 + 2 + (u&1)], srcl);
        pu[kp].u[u] = (l4 & 2) ? gB : gA;
      }

    // ---- rescale (wave-uniform skip) + swapped PV: mfma(V^T, P) ----
    if (__any(alpha != 1.0f)){
      #pragma unroll
      for (int dt=0;dt<16;dt++) oacc[dt] *= alpha;
    }
    #pragma unroll
    for (int dt=0;dt<16;dt++){
      const _Float16* vr = EVb + (size_t)(dt*16 + l15)*TE + s0 + l4*8;
      f16x8 v0 = *(const f16x8*)(vr);
      f16x8 v1 = *(const f16x8*)(vr + 32);
      oacc[dt] = __builtin_amdgcn_mfma_f32_16x16x32_f16(v0, pu[0].v, oacc[dt], 0,0,0);
      oacc[dt] = __builtin_amdgcn_mfma_f32_16x16x32_f16(v1, pu[1].v, oacc[dt], 0,0,0);
    }
  }

  // ---- epilogue: reduce lrun over l4 groups; H += O/l (lane q = l15) ----
  lrun += __shfl_xor(lrun, 16);
  lrun += __shfl_xor(lrun, 32);
  float linv = 1.f / lrun;
  float* hp = &H[((size_t)b*TD + t0 + mb + l15)*DIM];
  #pragma unroll
  for (int dt=0;dt<16;dt++){
    float4* p = (float4*)&hp[dt*16 + l4*4];
    float4 v = *p;
    v.x += oacc[dt][0]*linv;
    v.y += oacc[dt][1]*linv;
    v.z += oacc[dt][2]*linv;
    v.w += oacc[dt][3]*linv;
    *p = v;
  }
}

// ---------- output projection as fp16 MFMA: out = Pb @ (Wph+Wpl)^T + bias ----------
__global__ __launch_bounds__(256) void k_proj_mfma(const _Float16* __restrict__ Hin,
    const _Float16* __restrict__ Wh, const _Float16* __restrict__ Wl,
    const float* __restrict__ bias, float* __restrict__ out)
{
  int blk = blockIdx.x;                 // 1024: 32 b x 32 t-tiles
  int b = blk >> 5;
  int t0 = (blk & 31) << 6;
  int tid = threadIdx.x;
  int wave = tid >> 6, lane = tid & 63;
  int l15 = lane & 15, l4 = lane >> 4;
  int mb = wave << 4;

  f16x8 ah[8];
  const _Float16* hrow = Hin + ((size_t)b*TD + t0 + mb + l15)*DIM;
  #pragma unroll
  for (int kc=0;kc<8;kc++) ah[kc] = *(const f16x8*)(hrow + kc*32 + l4*8);

  #pragma unroll
  for (int nt=0; nt<5; nt++){
    size_t wrow = (size_t)(nt*16 + l15)*256 + l4*8;
    f32x4 a = (f32x4){0.f,0.f,0.f,0.f};
    #pragma unroll
    for (int kc=0;kc<8;kc++){
      f16x8 bh = *(const f16x8*)(Wh + wrow + kc*32);
      f16x8 bl = *(const f16x8*)(Wl + wrow + kc*32);
      a = __builtin_amdgcn_mfma_f32_16x16x32_f16(ah[kc], bh, a, 0,0,0);
      a = __builtin_amdgcn_mfma_f32_16x16x32_f16(ah[kc], bl, a, 0,0,0);
    }
    int n = nt*16 + l15;
    float bv = bias[n];
    #pragma unroll
    for (int r=0;r<4;r++){
      int t = t0 + mb + l4*4 + r;
      out[((size_t)b*TD + t)*INDIM + n] = a[r] + bv;
    }
  }
}

extern "C" void kernel_launch(void* const* d_in, const int* in_sizes, int n_in,
                              void* d_out, int out_size, void* d_ws, size_t ws_size,
                              hipStream_t stream) {
  const float* enc   = (const float*)d_in[0];
  const float* emb   = (const float*)d_in[1];
  const float* mel   = (const float*)d_in[2];
  const float* W_lin = (const float*)d_in[3];
  const float* b_lin = (const float*)d_in[4];
  const float* w0    = (const float*)d_in[5];
  const float* b0    = (const float*)d_in[6];
  const float* w1    = (const float*)d_in[7];
  const float* b1    = (const float*)d_in[8];
  const float* Wq    = (const float*)d_in[9];
  const float* bq    = (const float*)d_in[10];
  const float* Wp    = (const float*)d_in[11];
  const float* bp    = (const float*)d_in[12];
  float* out = (float*)d_out;

  const size_t NTOK = (size_t)BB*TD*DIM;           // 16.78M
  const size_t NE   = (size_t)BB*TE*DIM;           // 8.39M
  _Float16* Xb  = (_Float16*)d_ws;
  float*    H   = (float*)(Xb + NTOK);
  _Float16* Wf0 = (_Float16*)(H + NTOK);
  _Float16* Wf1 = Wf0 + (size_t)512*1280;
  _Float16* Wqh = Wf1 + (size_t)512*1280;
  _Float16* Wql = Wqh + 65536;
  _Float16* Wlh = Wql + 65536;                     // 256*96
  _Float16* Wll = Wlh + 24576;
  _Float16* Wph = Wll + 24576;                     // 80*256
  _Float16* Wpl = Wph + 20480;
  _Float16* Eh  = Xb;                              // after conv0 consumes Xb
  _Float16* EVt = Xb + NE;
  _Float16* Pb  = Xb;                              // after attn consumes Eh/EVt

  k_wprep    <<<2560, 256, 0, stream>>>(w0, Wf0);
  k_wprep    <<<2560, 256, 0, stream>>>(w1, Wf1);
  k_qwprep   <<<256,  256, 0, stream>>>(Wq, Wqh, Wql);
  k_lwprep   <<<96,   256, 0, stream>>>(W_lin, Wlh, Wll);
  k_pwprep   <<<80,   256, 0, stream>>>(Wp, Wph, Wpl);
  k_lin_mfma <<<1024, 256, 0, stream>>>(mel, Wlh, Wll, b_lin, Xb);
  k_conv_mfma<0,1><<<4096, 256, 0, stream>>>(Xb, Wf0, b0, H);
  k_eprep    <<<2048, 256, 0, stream>>>(enc, emb, Eh, EVt);
  k_attn     <<<1024, 256, 0, stream>>>(H, Wqh, Wql, bq, Eh, EVt);
  k_conv_mfma<1,0><<<4096, 256, 0, stream>>>(H, Wf1, b1, Pb);
  k_proj_mfma<<<1024, 256, 0, stream>>>(Pb, Wph, Wpl, bp, out);
}

// Round 5
// 1040.574 us; speedup vs baseline: 1.1075x; 1.1075x over previous
//
#include <hip/hip_runtime.h>
#include <math.h>

#define BB 32
#define TD 2048
#define TE 1024
#define DIM 256
#define INDIM 80

typedef __attribute__((ext_vector_type(8))) _Float16 f16x8;
typedef __attribute__((ext_vector_type(4))) float f32x4;

__device__ __forceinline__ float sigmoidf_(float x){ return 1.f/(1.f+__expf(-x)); }

__device__ __forceinline__ unsigned pack2h(float a, float b){
  union { _Float16 h[2]; unsigned u; } x;
  x.h[0] = (_Float16)a; x.h[1] = (_Float16)b;
  return x.u;
}

// async 16B global->LDS copy (direct DMA, no VGPR round-trip)
__device__ __forceinline__ void cp16(const _Float16* g, _Float16* l){
  __builtin_amdgcn_global_load_lds(
      (const __attribute__((address_space(1))) unsigned int*)g,
      (__attribute__((address_space(3))) unsigned int*)l, 16, 0, 0);
}

// ------- conv weight reorder: w(512,256,5) f32 -> Wf[o][tap*256+ic] fp16 -------
__global__ __launch_bounds__(256) void k_wprep(const float* __restrict__ w,
    _Float16* __restrict__ Wf)
{
  int i = blockIdx.x*256 + threadIdx.x;   // 512*1280
  int o = i / 1280;
  int kk = i - o*1280;
  int tap = kk >> 8, ic = kk & 255;
  Wf[i] = (_Float16)w[(size_t)o*1280 + ic*5 + tap];
}

// ------- Wq 2-term fp16 split (row-major 256x256) -------
__global__ __launch_bounds__(256) void k_qwprep(const float* __restrict__ W,
    _Float16* __restrict__ Wh, _Float16* __restrict__ Wl)
{
  int i = blockIdx.x*256 + threadIdx.x;   // 65536
  float f = W[i];
  _Float16 h = (_Float16)f;
  Wh[i] = h;
  Wl[i] = (_Float16)(f - (float)h);
}

// ------- W_lin 2-term fp16 split, padded: (256,80) -> [256][96] -------
__global__ __launch_bounds__(256) void k_lwprep(const float* __restrict__ W,
    _Float16* __restrict__ Wh, _Float16* __restrict__ Wl)
{
  int i = blockIdx.x*256 + threadIdx.x;   // 256*96
  int d = i / 96, k = i - d*96;
  float f = (k < INDIM) ? W[d*INDIM + k] : 0.f;
  _Float16 h = (_Float16)f;
  Wh[i] = h;
  Wl[i] = (_Float16)(f - (float)h);
}

// ------- W_proj 2-term fp16 split (row-major 80x256) -------
__global__ __launch_bounds__(256) void k_pwprep(const float* __restrict__ W,
    _Float16* __restrict__ Wh, _Float16* __restrict__ Wl)
{
  int i = blockIdx.x*256 + threadIdx.x;   // 80*256
  float f = W[i];
  _Float16 h = (_Float16)f;
  Wh[i] = h;
  Wl[i] = (_Float16)(f - (float)h);
}

// ------- enc prep: Eh = fp16(enc) [b][s][d];  EVt = fp16(enc+emb) transposed [b][d][s] ---
__global__ __launch_bounds__(256) void k_eprep(const float* __restrict__ enc,
    const float* __restrict__ emb, _Float16* __restrict__ Eh,
    _Float16* __restrict__ EVt)
{
  __shared__ float ls[64][65];
  int blk = blockIdx.x;                  // 32 b * 16 st * 4 dt = 2048
  int dt = blk & 3, st = (blk>>2) & 15, b = blk >> 6;
  int s0 = st*64, d0 = dt*64;
  int tid = threadIdx.x;
  for (int k=0;k<16;k++){
    int idx = k*256 + tid;
    int r = idx >> 6, c = idx & 63;
    size_t gi = ((size_t)b*TE + s0 + r)*DIM + d0 + c;
    float e = enc[gi];
    ls[r][c] = e + emb[gi];
    Eh[gi] = (_Float16)e;
  }
  __syncthreads();
  for (int k=0;k<16;k++){
    int idx = k*256 + tid;
    int r = idx >> 6, c = idx & 63;
    EVt[((size_t)b*DIM + d0 + r)*TE + s0 + c] = (_Float16)ls[c][r];
  }
}

// ---------- input linear + shift-right as fp16 MFMA: X = shift(mel) @ W_lin^T ----------
__global__ __launch_bounds__(256) void k_lin_mfma(const float* __restrict__ mel,
    const _Float16* __restrict__ Wh, const _Float16* __restrict__ Wl,
    const float* __restrict__ bias, _Float16* __restrict__ X)
{
  __shared__ __align__(16) _Float16 ms[64*104];   // 64 rows x 96 cols (pad 104)
  int blk = blockIdx.x;                 // 1024: 32 b x 32 t-tiles
  int b = blk >> 5;
  int t0 = (blk & 31) << 6;
  int tid = threadIdx.x;

  for (int i = tid; i < 64*12; i += 256){
    int row = i / 12, cg = (i - row*12) * 8;
    int t = t0 + row - 1;               // shifted: X[t] = lin(mel[t-1])
    f16x8 v = {};
    if (t >= 0 && cg < INDIM){
      const float4* p = (const float4*)(mel + ((size_t)b*TD + t)*INDIM + cg);
      float4 f0 = p[0], f1 = p[1];
      v[0]=(_Float16)f0.x; v[1]=(_Float16)f0.y; v[2]=(_Float16)f0.z; v[3]=(_Float16)f0.w;
      v[4]=(_Float16)f1.x; v[5]=(_Float16)f1.y; v[6]=(_Float16)f1.z; v[7]=(_Float16)f1.w;
    }
    *(f16x8*)&ms[row*104 + cg] = v;
  }
  __syncthreads();

  int wave = tid >> 6, lane = tid & 63;
  int l15 = lane & 15, l4 = lane >> 4;
  int mb = wave << 4;

  f16x8 am[3];
  #pragma unroll
  for (int kc=0;kc<3;kc++) am[kc] = *(f16x8*)&ms[(mb + l15)*104 + kc*32 + l4*8];

  for (int dt=0; dt<16; dt++){
    size_t wrow = (size_t)(dt*16 + l15)*96 + l4*8;
    f32x4 a = (f32x4){0.f,0.f,0.f,0.f};
    #pragma unroll
    for (int kc=0;kc<3;kc++){
      f16x8 bh = *(const f16x8*)(Wh + wrow + kc*32);
      f16x8 bl = *(const f16x8*)(Wl + wrow + kc*32);
      a = __builtin_amdgcn_mfma_f32_16x16x32_f16(am[kc], bh, a, 0,0,0);
      a = __builtin_amdgcn_mfma_f32_16x16x32_f16(am[kc], bl, a, 0,0,0);
    }
    int d = dt*16 + l15;
    float bv = bias[d];
    #pragma unroll
    for (int r=0;r<4;r++){
      int m = mb + l4*4 + r;
      int t = t0 + m;
      X[((size_t)b*TD + t)*DIM + d] = (t==0) ? (_Float16)0.f : (_Float16)(a[r] + bv);
    }
  }
}

// ---------------- conv-GLU as fp16 MFMA GEMM ----------------
template<int TIN_F32, int TOUT_F32>
__global__ __launch_bounds__(256) void k_conv_mfma(const void* __restrict__ Xin_,
    const _Float16* __restrict__ Wf, const float* __restrict__ bias,
    void* __restrict__ Hout_)
{
  __shared__ __align__(16) _Float16 as[68*264];   // 35.9 KB
  int id = blockIdx.x;
  int dtile = id & 3, mtile = id >> 2;
  int b = mtile >> 5;
  int t0 = (mtile & 31) << 6;
  int d0 = dtile << 6;
  int tid = threadIdx.x;

  for (int i = tid; i < 68*32; i += 256){
    int row = i >> 5, cg = (i & 31) << 3;
    int t = t0 - 4 + row;
    f16x8 v = {};
    if (t >= 0){
      if (TIN_F32){
        const float4* p = (const float4*)((const float*)Xin_ + ((size_t)b*TD + t)*DIM + cg);
        float4 f0 = p[0], f1 = p[1];
        v[0]=(_Float16)f0.x; v[1]=(_Float16)f0.y; v[2]=(_Float16)f0.z; v[3]=(_Float16)f0.w;
        v[4]=(_Float16)f1.x; v[5]=(_Float16)f1.y; v[6]=(_Float16)f1.z; v[7]=(_Float16)f1.w;
      } else {
        v = *(const f16x8*)((const _Float16*)Xin_ + ((size_t)b*TD + t)*DIM + cg);
      }
    }
    *(f16x8*)&as[row*264 + cg] = v;
  }
  __syncthreads();

  int lane = tid & 63, wave = tid >> 6;
  int l15 = lane & 15, l4 = lane >> 4;
  int dA = d0 + (wave << 4) + l15;

  const _Float16* pA = Wf + (size_t)dA*1280 + l4*8;
  const _Float16* pG = Wf + (size_t)(256 + dA)*1280 + l4*8;

  f32x4 aca[4], acg[4];
  #pragma unroll
  for (int mt=0;mt<4;mt++){ aca[mt]=(f32x4){0.f,0.f,0.f,0.f}; acg[mt]=(f32x4){0.f,0.f,0.f,0.f}; }

  f16x8 bA = *(const f16x8*)pA;
  f16x8 bG = *(const f16x8*)pG;
  #pragma unroll
  for (int kc = 0; kc < 40; ++kc){
    f16x8 nA = bA, nG = bG;
    if (kc < 39){
      nA = *(const f16x8*)(pA + (kc+1)*32);
      nG = *(const f16x8*)(pG + (kc+1)*32);
    }
    int tap = kc >> 3;
    int ic0 = (kc & 7) << 5;
    int abase = (l15 + tap)*264 + ic0 + l4*8;
    #pragma unroll
    for (int mt=0;mt<4;mt++){
      f16x8 av = *(f16x8*)&as[abase + mt*16*264];
      aca[mt] = __builtin_amdgcn_mfma_f32_16x16x32_f16(av, bA, aca[mt], 0,0,0);
      acg[mt] = __builtin_amdgcn_mfma_f32_16x16x32_f16(av, bG, acg[mt], 0,0,0);
    }
    bA = nA; bG = nG;
  }

  const float is2 = 0.7071067811865476f;
  float ba = bias[dA], bg = bias[256 + dA];
  #pragma unroll
  for (int mt=0; mt<4; mt++){
    #pragma unroll
    for (int r=0;r<4;r++){
      int m = mt*16 + l4*4 + r;
      size_t orow = ((size_t)b*TD + t0 + m)*DIM;
      float xr = TIN_F32 ? ((const float*)Xin_)[orow + dA]
                         : (float)as[(m+4)*264 + dA];
      float a = aca[mt][r] + ba;
      float g = acg[mt][r] + bg;
      float o = (a*sigmoidf_(g) + xr)*is2;
      if (TOUT_F32) ((float*)Hout_)[orow + dA] = o;
      else          ((_Float16*)Hout_)[orow + dA] = (_Float16)o;
    }
  }
}

// ---------- fused q-linear + flash attention + residual ----------
// Hybrid of R1 (staged K: async DMA, double-buffered, XOR-swizzled, 64-row chunks)
// and R4 (in-wave swapped-QK softmax + register P-redistribution + swapped PV).
// Each wave owns 16 q-rows end-to-end -> zero cross-wave data flow -> exactly ONE
// __syncthreads per chunk (K-buffer protection only). V direct from L2 (R1-proven).
// Defer-max (T13, THR=8) skips rescale on most chunks; setprio (T5) on MFMA.
__device__ __forceinline__ void stage_k(const _Float16* __restrict__ Ehb,
    _Float16* __restrict__ dst, int srow0, int wave, int lane)
{
  int r2 = lane >> 5, cu = lane & 31;
  #pragma unroll
  for (int ii=0; ii<8; ii++){
    int row = (ii*4 + wave)*2 + r2;                       // 0..63
    cp16(Ehb + (size_t)(srow0 + row)*DIM + ((cu ^ (row & 7)) << 3),
         dst + (ii*4 + wave)*512);                        // wave-uniform LDS base
  }
}

__global__ __launch_bounds__(256) void k_attn(float* __restrict__ H,
    const _Float16* __restrict__ Wqh, const _Float16* __restrict__ Wql,
    const float* __restrict__ bq,
    const _Float16* __restrict__ Eh, const _Float16* __restrict__ EVt)
{
  __shared__ __align__(16) _Float16 Kb[2][64*256];   // 64 KB total; Kb[0] doubles as Q transit

  int i = blockIdx.x;                   // XCD swizzle: same-batch blocks share an XCD
  int b = (i & 7) | ((i >> 8) << 3);
  int t0 = ((i >> 3) & 31) << 6;
  int tid = threadIdx.x;
  int wave = tid >> 6, lane = tid & 63;
  int l15 = lane & 15, l4 = lane >> 4;
  int mb = wave << 4;

  const _Float16* Ehb = Eh + (size_t)b*TE*DIM;
  const _Float16* EVb = EVt + (size_t)b*DIM*TE;

  // stage K chunk 0 into Kb[1] NOW — latency hides under the whole q-linear
  stage_k(Ehb, &Kb[1][0], 0, wave, lane);

  // ---- q-linear (2-term fp16) ----
  f16x8 ah[8];
  {
    const float* hrow = H + ((size_t)b*TD + t0 + mb + l15)*DIM;
    #pragma unroll
    for (int kc=0;kc<8;kc++){
      const float4* p = (const float4*)(hrow + kc*32 + l4*8);
      float4 f0 = p[0], f1 = p[1];
      f16x8 v;
      v[0]=(_Float16)f0.x; v[1]=(_Float16)f0.y; v[2]=(_Float16)f0.z; v[3]=(_Float16)f0.w;
      v[4]=(_Float16)f1.x; v[5]=(_Float16)f1.y; v[6]=(_Float16)f1.z; v[7]=(_Float16)f1.w;
      ah[kc] = v;
    }
  }

  f32x4 qacc[16];
  for (int ot=0;ot<16;ot++){
    size_t wrow = (size_t)(ot*16 + l15)*256 + l4*8;
    f32x4 a = (f32x4){0.f,0.f,0.f,0.f};
    #pragma unroll
    for (int kc=0;kc<8;kc++){
      f16x8 bh = *(const f16x8*)(Wqh + wrow + kc*32);
      f16x8 bl = *(const f16x8*)(Wql + wrow + kc*32);
      a = __builtin_amdgcn_mfma_f32_16x16x32_f16(ah[kc], bh, a, 0,0,0);
      a = __builtin_amdgcn_mfma_f32_16x16x32_f16(ah[kc], bl, a, 0,0,0);
    }
    qacc[ot] = a;
  }
  #pragma unroll
  for (int ot=0;ot<16;ot++){
    float bqv = bq[ot*16 + l15];
    #pragma unroll
    for (int r=0;r<4;r++) qacc[ot][r] += bqv;
  }

  // ---- Q hi/lo transit through Kb[0] (per-wave-private rows, XOR-swizzled,
  //      no barriers; Kb[1] DMA writes are disjoint) ----
  _Float16* Qt = &Kb[0][0];
  #pragma unroll
  for (int ot=0;ot<16;ot++){
    int o = ot*16 + l15;
    #pragma unroll
    for (int r=0;r<4;r++){
      int row = mb + l4*4 + r;
      Qt[row*256 + (o ^ ((row & 7) << 3))] = (_Float16)qacc[ot][r];
    }
  }
  f16x8 aqh[8];
  {
    int row = mb + l15, sw8 = l15 & 7;
    #pragma unroll
    for (int kc=0;kc<8;kc++)
      aqh[kc] = *(f16x8*)&Qt[row*256 + (((kc*4 + l4) ^ sw8) << 3)];
  }
  #pragma unroll
  for (int ot=0;ot<16;ot++){
    int o = ot*16 + l15;
    #pragma unroll
    for (int r=0;r<4;r++){
      int row = mb + l4*4 + r;
      float v = qacc[ot][r];
      _Float16 h = (_Float16)v;
      Qt[row*256 + (o ^ ((row & 7) << 3))] = (_Float16)(v - (float)h);
    }
  }
  f16x8 aql[8];
  {
    int row = mb + l15, sw8 = l15 & 7;
    #pragma unroll
    for (int kc=0;kc<8;kc++)
      aql[kc] = *(f16x8*)&Qt[row*256 + (((kc*4 + l4) ^ sw8) << 3)];
  }

  // all transit reads done + chunk-0 stage landed before anyone touches Kb in the loop
  asm volatile("s_waitcnt vmcnt(0) lgkmcnt(0)" ::: "memory");
  __syncthreads();

  // ---- main loop: 16 chunks of 64 s; ONE barrier per chunk ----
  f32x4 oacc[16];                        // (q = l15, d = dt*16 + l4*4 + r)
  #pragma unroll
  for (int dt=0;dt<16;dt++) oacc[dt] = (f32x4){0.f,0.f,0.f,0.f};
  float mrun = -3.0e38f, lrun = 0.f;     // per-lane: q = l15 (replicated over l4)
  int sw = l15 & 7;

  for (int c = 0; c < 16; ++c){
    int cur = (c & 1) ^ 1;               // chunk 0 lives in Kb[1]
    int s0 = c << 6;
    // prefetch next K chunk into the buffer QK(c-1) used; drains at loop-end barrier
    if (c < 15) stage_k(Ehb, &Kb[cur^1][0], s0 + 64, wave, lane);

    // ---- QK^T swapped: mfma(K_lds, Q) -> lane l15 = q, s = st*16 + l4*4 + r ----
    f32x4 sacc[4];
    __builtin_amdgcn_s_setprio(1);
    #pragma unroll
    for (int st=0;st<4;st++){
      const _Float16* kb = &Kb[cur][(st*16 + l15)*256];
      f32x4 a = (f32x4){0.f,0.f,0.f,0.f};
      #pragma unroll
      for (int kc=0;kc<8;kc++){
        f16x8 kf = *(const f16x8*)(kb + (((kc*4 + l4) ^ sw) << 3));
        a = __builtin_amdgcn_mfma_f32_16x16x32_f16(kf, aqh[kc], a, 0,0,0);
        a = __builtin_amdgcn_mfma_f32_16x16x32_f16(kf, aql[kc], a, 0,0,0);
      }
      sacc[st] = a;
    }
    __builtin_amdgcn_s_setprio(0);

    // ---- in-lane online softmax with defer-max (THR=8) ----
    float cm = sacc[0][0];
    #pragma unroll
    for (int st=0;st<4;st++)
      #pragma unroll
      for (int r=0;r<4;r++) cm = fmaxf(cm, sacc[st][r]);
    cm = fmaxf(cm, __shfl_xor(cm, 16));
    cm = fmaxf(cm, __shfl_xor(cm, 32));
    bool need = __any(cm > mrun + 8.f);
    float mnew = need ? fmaxf(mrun, cm) : mrun;
    float alpha = need ? __expf(mrun - mnew) : 1.f;
    mrun = mnew;
    float ps[4][4];
    float lp = 0.f;
    #pragma unroll
    for (int st=0;st<4;st++)
      #pragma unroll
      for (int r=0;r<4;r++){
        float p = __expf(sacc[st][r] - mnew);
        ps[st][r] = p;
        lp += p;
      }
    lrun = lrun*alpha + lp;              // per-lane partial over own l4-group's s

    // ---- pack P to fp16 pairs and redistribute to PV B-fragment layout ----
    // pair index p = kp*16 + l4'*4 + u; source j = kp*4 + (l4'>>1)*2 + (u&1);
    // source lane l4s = (l4'*2+(u>>1))&3. Pull both j and j+2, select by l4&2.
    unsigned pk[8];
    #pragma unroll
    for (int st=0;st<4;st++){
      pk[st*2+0] = pack2h(ps[st][0], ps[st][1]);
      pk[st*2+1] = pack2h(ps[st][2], ps[st][3]);
    }
    union { f16x8 v; unsigned u[4]; } pu[2];
    #pragma unroll
    for (int kp=0;kp<2;kp++)
      #pragma unroll
      for (int u=0;u<4;u++){
        int srcl = l15 + (((l4*2 + (u>>1)) & 3) << 4);
        unsigned gA = (unsigned)__shfl((int)pk[kp*4 + (u&1)], srcl);
        unsigned gB = (unsigned)__shfl((int)pk[kp*4 + 2 + (u&1)], srcl);
        pu[kp].u[u] = (l4 & 2) ? gB : gA;
      }

    // ---- rescale (usually skipped) + swapped PV: mfma(V^T, P), V direct from L2 ----
    if (need){
      #pragma unroll
      for (int dt=0;dt<16;dt++) oacc[dt] *= alpha;
    }
    __builtin_amdgcn_s_setprio(1);
    #pragma unroll
    for (int dt=0;dt<16;dt++){
      const _Float16* vr = EVb + (size_t)(dt*16 + l15)*TE + s0 + l4*8;
      f16x8 v0 = *(const f16x8*)(vr);
      f16x8 v1 = *(const f16x8*)(vr + 32);
      oacc[dt] = __builtin_amdgcn_mfma_f32_16x16x32_f16(v0, pu[0].v, oacc[dt], 0,0,0);
      oacc[dt] = __builtin_amdgcn_mfma_f32_16x16x32_f16(v1, pu[1].v, oacc[dt], 0,0,0);
    }
    __builtin_amdgcn_s_setprio(0);

    // one barrier per chunk: own stage(c+1) drained (syncthreads emits vmcnt0/lgkm0),
    // all waves' Kb[cur] reads complete -> next chunk may overwrite Kb[cur]
    __syncthreads();
  }

  // ---- epilogue: reduce lrun over l4 groups; H += O/l (lane q = l15) ----
  lrun += __shfl_xor(lrun, 16);
  lrun += __shfl_xor(lrun, 32);
  float linv = 1.f / lrun;
  float* hp = &H[((size_t)b*TD + t0 + mb + l15)*DIM];
  #pragma unroll
  for (int dt=0;dt<16;dt++){
    float4* p = (float4*)&hp[dt*16 + l4*4];
    float4 v = *p;
    v.x += oacc[dt][0]*linv;
    v.y += oacc[dt][1]*linv;
    v.z += oacc[dt][2]*linv;
    v.w += oacc[dt][3]*linv;
    *p = v;
  }
}

// ---------- output projection as fp16 MFMA: out = Pb @ (Wph+Wpl)^T + bias ----------
__global__ __launch_bounds__(256) void k_proj_mfma(const _Float16* __restrict__ Hin,
    const _Float16* __restrict__ Wh, const _Float16* __restrict__ Wl,
    const float* __restrict__ bias, float* __restrict__ out)
{
  int blk = blockIdx.x;                 // 1024: 32 b x 32 t-tiles
  int b = blk >> 5;
  int t0 = (blk & 31) << 6;
  int tid = threadIdx.x;
  int wave = tid >> 6, lane = tid & 63;
  int l15 = lane & 15, l4 = lane >> 4;
  int mb = wave << 4;

  f16x8 ah[8];
  const _Float16* hrow = Hin + ((size_t)b*TD + t0 + mb + l15)*DIM;
  #pragma unroll
  for (int kc=0;kc<8;kc++) ah[kc] = *(const f16x8*)(hrow + kc*32 + l4*8);

  #pragma unroll
  for (int nt=0; nt<5; nt++){
    size_t wrow = (size_t)(nt*16 + l15)*256 + l4*8;
    f32x4 a = (f32x4){0.f,0.f,0.f,0.f};
    #pragma unroll
    for (int kc=0;kc<8;kc++){
      f16x8 bh = *(const f16x8*)(Wh + wrow + kc*32);
      f16x8 bl = *(const f16x8*)(Wl + wrow + kc*32);
      a = __builtin_amdgcn_mfma_f32_16x16x32_f16(ah[kc], bh, a, 0,0,0);
      a = __builtin_amdgcn_mfma_f32_16x16x32_f16(ah[kc], bl, a, 0,0,0);
    }
    int n = nt*16 + l15;
    float bv = bias[n];
    #pragma unroll
    for (int r=0;r<4;r++){
      int t = t0 + mb + l4*4 + r;
      out[((size_t)b*TD + t)*INDIM + n] = a[r] + bv;
    }
  }
}

extern "C" void kernel_launch(void* const* d_in, const int* in_sizes, int n_in,
                              void* d_out, int out_size, void* d_ws, size_t ws_size,
                              hipStream_t stream) {
  const float* enc   = (const float*)d_in[0];
  const float* emb   = (const float*)d_in[1];
  const float* mel   = (const float*)d_in[2];
  const float* W_lin = (const float*)d_in[3];
  const float* b_lin = (const float*)d_in[4];
  const float* w0    = (const float*)d_in[5];
  const float* b0    = (const float*)d_in[6];
  const float* w1    = (const float*)d_in[7];
  const float* b1    = (const float*)d_in[8];
  const float* Wq    = (const float*)d_in[9];
  const float* bq    = (const float*)d_in[10];
  const float* Wp    = (const float*)d_in[11];
  const float* bp    = (const float*)d_in[12];
  float* out = (float*)d_out;

  const size_t NTOK = (size_t)BB*TD*DIM;           // 16.78M
  const size_t NE   = (size_t)BB*TE*DIM;           // 8.39M
  _Float16* Xb  = (_Float16*)d_ws;
  float*    H   = (float*)(Xb + NTOK);
  _Float16* Wf0 = (_Float16*)(H + NTOK);
  _Float16* Wf1 = Wf0 + (size_t)512*1280;
  _Float16* Wqh = Wf1 + (size_t)512*1280;
  _Float16* Wql = Wqh + 65536;
  _Float16* Wlh = Wql + 65536;                     // 256*96
  _Float16* Wll = Wlh + 24576;
  _Float16* Wph = Wll + 24576;                     // 80*256
  _Float16* Wpl = Wph + 20480;
  _Float16* Eh  = Xb;                              // after conv0 consumes Xb
  _Float16* EVt = Xb + NE;
  _Float16* Pb  = Xb;                              // after attn consumes Eh/EVt

  k_wprep    <<<2560, 256, 0, stream>>>(w0, Wf0);
  k_wprep    <<<2560, 256, 0, stream>>>(w1, Wf1);
  k_qwprep   <<<256,  256, 0, stream>>>(Wq, Wqh, Wql);
  k_lwprep   <<<96,   256, 0, stream>>>(W_lin, Wlh, Wll);
  k_pwprep   <<<80,   256, 0, stream>>>(Wp, Wph, Wpl);
  k_lin_mfma <<<1024, 256, 0, stream>>>(mel, Wlh, Wll, b_lin, Xb);
  k_conv_mfma<0,1><<<4096, 256, 0, stream>>>(Xb, Wf0, b0, H);
  k_eprep    <<<2048, 256, 0, stream>>>(enc, emb, Eh, EVt);
  k_attn     <<<1024, 256, 0, stream>>>(H, Wqh, Wql, bq, Eh, EVt);
  k_conv_mfma<1,0><<<4096, 256, 0, stream>>>(H, Wf1, b1, Pb);
  k_proj_mfma<<<1024, 256, 0, stream>>>(Pb, Wph, Wpl, bp, out);
}

// Round 6
// 891.188 us; speedup vs baseline: 1.2932x; 1.1676x over previous
//
#include <hip/hip_runtime.h>
#include <math.h>

#define BB 32
#define TD 2048
#define TE 1024
#define DIM 256
#define INDIM 80

typedef __attribute__((ext_vector_type(8))) _Float16 f16x8;
typedef __attribute__((ext_vector_type(4))) float f32x4;

__device__ __forceinline__ float sigmoidf_(float x){ return 1.f/(1.f+__expf(-x)); }

__device__ __forceinline__ unsigned pack2h(float a, float b){
  union { _Float16 h[2]; unsigned u; } x;
  x.h[0] = (_Float16)a; x.h[1] = (_Float16)b;
  return x.u;
}

// async 16B global->LDS copy (direct DMA, no VGPR round-trip)
__device__ __forceinline__ void cp16(const _Float16* g, _Float16* l){
  __builtin_amdgcn_global_load_lds(
      (const __attribute__((address_space(1))) unsigned int*)g,
      (__attribute__((address_space(3))) unsigned int*)l, 16, 0, 0);
}

// ------- conv weight reorder: w(512,256,5) f32 -> Wf[o][tap*256+ic] fp16 -------
__global__ __launch_bounds__(256) void k_wprep(const float* __restrict__ w,
    _Float16* __restrict__ Wf)
{
  int i = blockIdx.x*256 + threadIdx.x;   // 512*1280
  int o = i / 1280;
  int kk = i - o*1280;
  int tap = kk >> 8, ic = kk & 255;
  Wf[i] = (_Float16)w[(size_t)o*1280 + ic*5 + tap];
}

// ------- Wq 2-term fp16 split (row-major 256x256) -------
__global__ __launch_bounds__(256) void k_qwprep(const float* __restrict__ W,
    _Float16* __restrict__ Wh, _Float16* __restrict__ Wl)
{
  int i = blockIdx.x*256 + threadIdx.x;   // 65536
  float f = W[i];
  _Float16 h = (_Float16)f;
  Wh[i] = h;
  Wl[i] = (_Float16)(f - (float)h);
}

// ------- W_lin 2-term fp16 split, padded: (256,80) -> [256][96] -------
__global__ __launch_bounds__(256) void k_lwprep(const float* __restrict__ W,
    _Float16* __restrict__ Wh, _Float16* __restrict__ Wl)
{
  int i = blockIdx.x*256 + threadIdx.x;   // 256*96
  int d = i / 96, k = i - d*96;
  float f = (k < INDIM) ? W[d*INDIM + k] : 0.f;
  _Float16 h = (_Float16)f;
  Wh[i] = h;
  Wl[i] = (_Float16)(f - (float)h);
}

// ------- W_proj 2-term fp16 split (row-major 80x256) -------
__global__ __launch_bounds__(256) void k_pwprep(const float* __restrict__ W,
    _Float16* __restrict__ Wh, _Float16* __restrict__ Wl)
{
  int i = blockIdx.x*256 + threadIdx.x;   // 80*256
  float f = W[i];
  _Float16 h = (_Float16)f;
  Wh[i] = h;
  Wl[i] = (_Float16)(f - (float)h);
}

// ------- enc prep: Eh = fp16(enc) [b][s][d];  EVt = fp16(enc+emb) transposed [b][d][s] ---
__global__ __launch_bounds__(256) void k_eprep(const float* __restrict__ enc,
    const float* __restrict__ emb, _Float16* __restrict__ Eh,
    _Float16* __restrict__ EVt)
{
  __shared__ float ls[64][65];
  int blk = blockIdx.x;                  // 32 b * 16 st * 4 dt = 2048
  int dt = blk & 3, st = (blk>>2) & 15, b = blk >> 6;
  int s0 = st*64, d0 = dt*64;
  int tid = threadIdx.x;
  for (int k=0;k<16;k++){
    int idx = k*256 + tid;
    int r = idx >> 6, c = idx & 63;
    size_t gi = ((size_t)b*TE + s0 + r)*DIM + d0 + c;
    float e = enc[gi];
    ls[r][c] = e + emb[gi];
    Eh[gi] = (_Float16)e;
  }
  __syncthreads();
  for (int k=0;k<16;k++){
    int idx = k*256 + tid;
    int r = idx >> 6, c = idx & 63;
    EVt[((size_t)b*DIM + d0 + r)*TE + s0 + c] = (_Float16)ls[c][r];
  }
}

// ---------- input linear + shift-right as fp16 MFMA: X = shift(mel) @ W_lin^T ----------
__global__ __launch_bounds__(256) void k_lin_mfma(const float* __restrict__ mel,
    const _Float16* __restrict__ Wh, const _Float16* __restrict__ Wl,
    const float* __restrict__ bias, _Float16* __restrict__ X)
{
  __shared__ __align__(16) _Float16 ms[64*104];   // 64 rows x 96 cols (pad 104)
  int blk = blockIdx.x;                 // 1024: 32 b x 32 t-tiles
  int b = blk >> 5;
  int t0 = (blk & 31) << 6;
  int tid = threadIdx.x;

  for (int i = tid; i < 64*12; i += 256){
    int row = i / 12, cg = (i - row*12) * 8;
    int t = t0 + row - 1;               // shifted: X[t] = lin(mel[t-1])
    f16x8 v = {};
    if (t >= 0 && cg < INDIM){
      const float4* p = (const float4*)(mel + ((size_t)b*TD + t)*INDIM + cg);
      float4 f0 = p[0], f1 = p[1];
      v[0]=(_Float16)f0.x; v[1]=(_Float16)f0.y; v[2]=(_Float16)f0.z; v[3]=(_Float16)f0.w;
      v[4]=(_Float16)f1.x; v[5]=(_Float16)f1.y; v[6]=(_Float16)f1.z; v[7]=(_Float16)f1.w;
    }
    *(f16x8*)&ms[row*104 + cg] = v;
  }
  __syncthreads();

  int wave = tid >> 6, lane = tid & 63;
  int l15 = lane & 15, l4 = lane >> 4;
  int mb = wave << 4;

  f16x8 am[3];
  #pragma unroll
  for (int kc=0;kc<3;kc++) am[kc] = *(f16x8*)&ms[(mb + l15)*104 + kc*32 + l4*8];

  for (int dt=0; dt<16; dt++){
    size_t wrow = (size_t)(dt*16 + l15)*96 + l4*8;
    f32x4 a = (f32x4){0.f,0.f,0.f,0.f};
    #pragma unroll
    for (int kc=0;kc<3;kc++){
      f16x8 bh = *(const f16x8*)(Wh + wrow + kc*32);
      f16x8 bl = *(const f16x8*)(Wl + wrow + kc*32);
      a = __builtin_amdgcn_mfma_f32_16x16x32_f16(am[kc], bh, a, 0,0,0);
      a = __builtin_amdgcn_mfma_f32_16x16x32_f16(am[kc], bl, a, 0,0,0);
    }
    int d = dt*16 + l15;
    float bv = bias[d];
    #pragma unroll
    for (int r=0;r<4;r++){
      int m = mb + l4*4 + r;
      int t = t0 + m;
      X[((size_t)b*TD + t)*DIM + d] = (t==0) ? (_Float16)0.f : (_Float16)(a[r] + bv);
    }
  }
}

// ---------------- conv-GLU as fp16 MFMA GEMM ----------------
template<int TIN_F32, int TOUT_F32>
__global__ __launch_bounds__(256) void k_conv_mfma(const void* __restrict__ Xin_,
    const _Float16* __restrict__ Wf, const float* __restrict__ bias,
    void* __restrict__ Hout_)
{
  __shared__ __align__(16) _Float16 as[68*264];   // 35.9 KB
  int id = blockIdx.x;
  int dtile = id & 3, mtile = id >> 2;
  int b = mtile >> 5;
  int t0 = (mtile & 31) << 6;
  int d0 = dtile << 6;
  int tid = threadIdx.x;

  for (int i = tid; i < 68*32; i += 256){
    int row = i >> 5, cg = (i & 31) << 3;
    int t = t0 - 4 + row;
    f16x8 v = {};
    if (t >= 0){
      if (TIN_F32){
        const float4* p = (const float4*)((const float*)Xin_ + ((size_t)b*TD + t)*DIM + cg);
        float4 f0 = p[0], f1 = p[1];
        v[0]=(_Float16)f0.x; v[1]=(_Float16)f0.y; v[2]=(_Float16)f0.z; v[3]=(_Float16)f0.w;
        v[4]=(_Float16)f1.x; v[5]=(_Float16)f1.y; v[6]=(_Float16)f1.z; v[7]=(_Float16)f1.w;
      } else {
        v = *(const f16x8*)((const _Float16*)Xin_ + ((size_t)b*TD + t)*DIM + cg);
      }
    }
    *(f16x8*)&as[row*264 + cg] = v;
  }
  __syncthreads();

  int lane = tid & 63, wave = tid >> 6;
  int l15 = lane & 15, l4 = lane >> 4;
  int dA = d0 + (wave << 4) + l15;

  const _Float16* pA = Wf + (size_t)dA*1280 + l4*8;
  const _Float16* pG = Wf + (size_t)(256 + dA)*1280 + l4*8;

  f32x4 aca[4], acg[4];
  #pragma unroll
  for (int mt=0;mt<4;mt++){ aca[mt]=(f32x4){0.f,0.f,0.f,0.f}; acg[mt]=(f32x4){0.f,0.f,0.f,0.f}; }

  f16x8 bA = *(const f16x8*)pA;
  f16x8 bG = *(const f16x8*)pG;
  #pragma unroll
  for (int kc = 0; kc < 40; ++kc){
    f16x8 nA = bA, nG = bG;
    if (kc < 39){
      nA = *(const f16x8*)(pA + (kc+1)*32);
      nG = *(const f16x8*)(pG + (kc+1)*32);
    }
    int tap = kc >> 3;
    int ic0 = (kc & 7) << 5;
    int abase = (l15 + tap)*264 + ic0 + l4*8;
    #pragma unroll
    for (int mt=0;mt<4;mt++){
      f16x8 av = *(f16x8*)&as[abase + mt*16*264];
      aca[mt] = __builtin_amdgcn_mfma_f32_16x16x32_f16(av, bA, aca[mt], 0,0,0);
      acg[mt] = __builtin_amdgcn_mfma_f32_16x16x32_f16(av, bG, acg[mt], 0,0,0);
    }
    bA = nA; bG = nG;
  }

  const float is2 = 0.7071067811865476f;
  float ba = bias[dA], bg = bias[256 + dA];
  #pragma unroll
  for (int mt=0; mt<4; mt++){
    #pragma unroll
    for (int r=0;r<4;r++){
      int m = mt*16 + l4*4 + r;
      size_t orow = ((size_t)b*TD + t0 + m)*DIM;
      float xr = TIN_F32 ? ((const float*)Xin_)[orow + dA]
                         : (float)as[(m+4)*264 + dA];
      float a = aca[mt][r] + ba;
      float g = acg[mt][r] + bg;
      float o = (a*sigmoidf_(g) + xr)*is2;
      if (TOUT_F32) ((float*)Hout_)[orow + dA] = o;
      else          ((_Float16*)Hout_)[orow + dA] = (_Float16)o;
    }
  }
}

// ---------- fused q-linear + flash attention + residual ----------
// R1 pipeline (staged K via DMA double-buffer, d-split prefetched V, 2 barriers/chunk)
// + R4-proven in-lane softmax (swapped QK: mfma(K,Q) puts q at lane l15) + defer-max.
// P crosses waves once per chunk through swizzled pb[64][72]; alphas/linvs via LDS.
// V loads issued BEFORE stage DMAs so the counted vmcnt wait for V leaves K-prefetch
// in flight until the loop-end __syncthreads.
__device__ __forceinline__ void stage_k(const _Float16* __restrict__ Ehb,
    _Float16* __restrict__ dst, int srow0, int wave, int lane)
{
  int r2 = lane >> 5, cu = lane & 31;
  #pragma unroll
  for (int ii=0; ii<8; ii++){
    int row = (ii*4 + wave)*2 + r2;                       // 0..63
    cp16(Ehb + (size_t)(srow0 + row)*DIM + ((cu ^ (row & 7)) << 3),
         dst + (ii*4 + wave)*512);                        // wave-uniform LDS base
  }
}

__global__ __launch_bounds__(256) void k_attn(float* __restrict__ H,
    const _Float16* __restrict__ Wqh, const _Float16* __restrict__ Wql,
    const float* __restrict__ bq,
    const _Float16* __restrict__ Eh, const _Float16* __restrict__ EVt)
{
  __shared__ __align__(16) _Float16 Kb[2][64*256];   // 64 KB; Kb[0] doubles as Q transit
  __shared__ __align__(16) _Float16 pb[64][72];      // 9 KB P exchange (XOR-swizzled)
  __shared__ float alphas[64];
  __shared__ float linvs[64];

  int i = blockIdx.x;                   // XCD swizzle: same-batch blocks share an XCD
  int b = (i & 7) | ((i >> 8) << 3);
  int t0 = ((i >> 3) & 31) << 6;
  int tid = threadIdx.x;
  int wave = tid >> 6, lane = tid & 63;
  int l15 = lane & 15, l4 = lane >> 4;
  int mb = wave << 4;

  const _Float16* Ehb = Eh + (size_t)b*TE*DIM;
  const _Float16* EVb = EVt + (size_t)b*DIM*TE;

  // stage K chunk 0 into Kb[1] NOW — latency hides under the whole q-linear
  stage_k(Ehb, &Kb[1][0], 0, wave, lane);

  // ---- q-linear (2-term fp16) ----
  f16x8 ah[8];
  {
    const float* hrow = H + ((size_t)b*TD + t0 + mb + l15)*DIM;
    #pragma unroll
    for (int kc=0;kc<8;kc++){
      const float4* p = (const float4*)(hrow + kc*32 + l4*8);
      float4 f0 = p[0], f1 = p[1];
      f16x8 v;
      v[0]=(_Float16)f0.x; v[1]=(_Float16)f0.y; v[2]=(_Float16)f0.z; v[3]=(_Float16)f0.w;
      v[4]=(_Float16)f1.x; v[5]=(_Float16)f1.y; v[6]=(_Float16)f1.z; v[7]=(_Float16)f1.w;
      ah[kc] = v;
    }
  }

  f32x4 qacc[16];
  for (int ot=0;ot<16;ot++){
    size_t wrow = (size_t)(ot*16 + l15)*256 + l4*8;
    f32x4 a = (f32x4){0.f,0.f,0.f,0.f};
    #pragma unroll
    for (int kc=0;kc<8;kc++){
      f16x8 bh = *(const f16x8*)(Wqh + wrow + kc*32);
      f16x8 bl = *(const f16x8*)(Wql + wrow + kc*32);
      a = __builtin_amdgcn_mfma_f32_16x16x32_f16(ah[kc], bh, a, 0,0,0);
      a = __builtin_amdgcn_mfma_f32_16x16x32_f16(ah[kc], bl, a, 0,0,0);
    }
    qacc[ot] = a;
  }
  #pragma unroll
  for (int ot=0;ot<16;ot++){
    float bqv = bq[ot*16 + l15];
    #pragma unroll
    for (int r=0;r<4;r++) qacc[ot][r] += bqv;
  }

  // ---- Q hi/lo transit through Kb[0] (per-wave-private rows, XOR-swizzled) ----
  _Float16* Qt = &Kb[0][0];
  #pragma unroll
  for (int ot=0;ot<16;ot++){
    int o = ot*16 + l15;
    #pragma unroll
    for (int r=0;r<4;r++){
      int row = mb + l4*4 + r;
      Qt[row*256 + (o ^ ((row & 7) << 3))] = (_Float16)qacc[ot][r];
    }
  }
  f16x8 aqh[8];
  {
    int row = mb + l15, sw8 = l15 & 7;
    #pragma unroll
    for (int kc=0;kc<8;kc++)
      aqh[kc] = *(f16x8*)&Qt[row*256 + (((kc*4 + l4) ^ sw8) << 3)];
  }
  #pragma unroll
  for (int ot=0;ot<16;ot++){
    int o = ot*16 + l15;
    #pragma unroll
    for (int r=0;r<4;r++){
      int row = mb + l4*4 + r;
      float v = qacc[ot][r];
      _Float16 h = (_Float16)v;
      Qt[row*256 + (o ^ ((row & 7) << 3))] = (_Float16)(v - (float)h);
    }
  }
  f16x8 aql[8];
  {
    int row = mb + l15, sw8 = l15 & 7;
    #pragma unroll
    for (int kc=0;kc<8;kc++)
      aql[kc] = *(f16x8*)&Qt[row*256 + (((kc*4 + l4) ^ sw8) << 3)];
  }

  // transit reads done + chunk-0 stage landed before the loop touches Kb
  asm volatile("s_waitcnt vmcnt(0) lgkmcnt(0)" ::: "memory");
  __syncthreads();

  // ---- main loop: 16 chunks of 64 s ----
  f32x4 oacc[4][4];                      // [m-tile][d-tile]; wave owns d in [dq, dq+64)
  #pragma unroll
  for (int mt=0;mt<4;mt++)
    #pragma unroll
    for (int dt=0;dt<4;dt++) oacc[mt][dt] = (f32x4){0.f,0.f,0.f,0.f};
  float mrun = -3.0e38f, lrun = 0.f;     // per-lane: q = mb+l15 (partial over l4)
  int dq = wave << 6;
  int sw = l15 & 7;

  for (int c = 0; c < 16; ++c){
    int cur = (c & 1) ^ 1;               // chunk 0 lives in Kb[1]
    int s0 = c << 6;

    // V fragments for this wave's d-quarter (issued FIRST so the vmcnt wait for
    // them leaves the later stage-DMAs in flight); consumed after barrier #1
    f16x8 vv[2][4];
    #pragma unroll
    for (int kp=0;kp<2;kp++)
      #pragma unroll
      for (int dt=0;dt<4;dt++)
        vv[kp][dt] = *(const f16x8*)(EVb + (size_t)(dq + dt*16 + l15)*TE + s0 + kp*32 + l4*8);

    // prefetch next K chunk; drains at loop-end __syncthreads
    if (c < 15) stage_k(Ehb, &Kb[cur^1][0], s0 + 64, wave, lane);

    // ---- QK^T swapped: mfma(K_lds, Q) -> lane l15 = q, s = st*16 + l4*4 + r ----
    f32x4 sacc[4];
    __builtin_amdgcn_s_setprio(1);
    #pragma unroll
    for (int st=0;st<4;st++){
      const _Float16* kb = &Kb[cur][(st*16 + l15)*256];
      f32x4 a = (f32x4){0.f,0.f,0.f,0.f};
      #pragma unroll
      for (int kc=0;kc<8;kc++){
        f16x8 kf = *(const f16x8*)(kb + (((kc*4 + l4) ^ sw) << 3));
        a = __builtin_amdgcn_mfma_f32_16x16x32_f16(kf, aqh[kc], a, 0,0,0);
        a = __builtin_amdgcn_mfma_f32_16x16x32_f16(kf, aql[kc], a, 0,0,0);
      }
      sacc[st] = a;
    }
    __builtin_amdgcn_s_setprio(0);

    // ---- in-lane online softmax with defer-max (THR=8) ----
    float cm = sacc[0][0];
    #pragma unroll
    for (int st=0;st<4;st++)
      #pragma unroll
      for (int r=0;r<4;r++) cm = fmaxf(cm, sacc[st][r]);
    cm = fmaxf(cm, __shfl_xor(cm, 16));
    cm = fmaxf(cm, __shfl_xor(cm, 32));
    bool needw = __any(cm > mrun + 8.f);
    float mnew = needw ? fmaxf(mrun, cm) : mrun;
    float alpha = needw ? __expf(mrun - mnew) : 1.f;
    mrun = mnew;
    float ps[4][4];
    float lp = 0.f;
    #pragma unroll
    for (int st=0;st<4;st++)
      #pragma unroll
      for (int r=0;r<4;r++){
        float p = __expf(sacc[st][r] - mnew);
        ps[st][r] = p;
        lp += p;
      }
    lrun = lrun*alpha + lp;              // partial over own l4-group's s

    // ---- publish P (row q = mb+l15, elems s = st*16+l4*4.., XOR-swizzled) + alpha ----
    {
      int row = mb + l15;
      int s8 = (row & 7) << 3;
      _Float16* pr = &pb[row][0];
      #pragma unroll
      for (int st=0;st<4;st++){
        int eo = (st*16 + l4*4) ^ s8;
        *(unsigned*)&pr[eo]     = pack2h(ps[st][0], ps[st][1]);
        *(unsigned*)&pr[eo + 2] = pack2h(ps[st][2], ps[st][3]);
      }
      if (l4 == 0) alphas[row] = alpha;
    }
    // barrier #1: LDS writes visible; K-prefetch + V loads stay in flight
    asm volatile("s_waitcnt lgkmcnt(0)" ::: "memory");
    __builtin_amdgcn_s_barrier();

    // ---- rescale (skipped when no row saw a new max) + PV (d-split) ----
    float avs[4][4];
    bool need2 = false;
    #pragma unroll
    for (int mt=0;mt<4;mt++)
      #pragma unroll
      for (int r=0;r<4;r++){
        float av = alphas[mt*16 + l4*4 + r];
        avs[mt][r] = av;
        need2 |= (av != 1.0f);
      }
    if (__any(need2)){
      #pragma unroll
      for (int mt=0;mt<4;mt++)
        #pragma unroll
        for (int r=0;r<4;r++){
          float av = avs[mt][r];
          #pragma unroll
          for (int dt=0;dt<4;dt++) oacc[mt][dt][r] *= av;
        }
    }
    __builtin_amdgcn_s_setprio(1);
    #pragma unroll
    for (int kp=0;kp<2;kp++){
      f16x8 pa[4];
      #pragma unroll
      for (int mt=0;mt<4;mt++){
        int row = mt*16 + l15;
        pa[mt] = *(f16x8*)&pb[row][(kp*32 + l4*8) ^ ((row & 7) << 3)];
      }
      #pragma unroll
      for (int dt=0;dt<4;dt++){
        #pragma unroll
        for (int mt=0;mt<4;mt++)
          oacc[mt][dt] = __builtin_amdgcn_mfma_f32_16x16x32_f16(pa[mt], vv[kp][dt], oacc[mt][dt], 0,0,0);
      }
    }
    __builtin_amdgcn_s_setprio(0);
    // barrier #2: pb reads done + K prefetch drained before next chunk
    __syncthreads();
  }

  // ---- epilogue: reduce lrun partials, publish 1/l, then H += O/l ----
  lrun += __shfl_xor(lrun, 16);
  lrun += __shfl_xor(lrun, 32);
  if (l4 == 0) linvs[mb + l15] = 1.f / lrun;
  __syncthreads();
  #pragma unroll
  for (int mt=0;mt<4;mt++){
    #pragma unroll
    for (int r=0;r<4;r++){
      float li = linvs[mt*16 + l4*4 + r];
      int t = t0 + mt*16 + l4*4 + r;
      float* hp = &H[((size_t)b*TD + t)*DIM + dq];
      #pragma unroll
      for (int dt=0;dt<4;dt++)
        hp[dt*16 + l15] += oacc[mt][dt][r] * li;
    }
  }
}

// ---------- output projection as fp16 MFMA: out = Pb @ (Wph+Wpl)^T + bias ----------
__global__ __launch_bounds__(256) void k_proj_mfma(const _Float16* __restrict__ Hin,
    const _Float16* __restrict__ Wh, const _Float16* __restrict__ Wl,
    const float* __restrict__ bias, float* __restrict__ out)
{
  int blk = blockIdx.x;                 // 1024: 32 b x 32 t-tiles
  int b = blk >> 5;
  int t0 = (blk & 31) << 6;
  int tid = threadIdx.x;
  int wave = tid >> 6, lane = tid & 63;
  int l15 = lane & 15, l4 = lane >> 4;
  int mb = wave << 4;

  f16x8 ah[8];
  const _Float16* hrow = Hin + ((size_t)b*TD + t0 + mb + l15)*DIM;
  #pragma unroll
  for (int kc=0;kc<8;kc++) ah[kc] = *(const f16x8*)(hrow + kc*32 + l4*8);

  #pragma unroll
  for (int nt=0; nt<5; nt++){
    size_t wrow = (size_t)(nt*16 + l15)*256 + l4*8;
    f32x4 a = (f32x4){0.f,0.f,0.f,0.f};
    #pragma unroll
    for (int kc=0;kc<8;kc++){
      f16x8 bh = *(const f16x8*)(Wh + wrow + kc*32);
      f16x8 bl = *(const f16x8*)(Wl + wrow + kc*32);
      a = __builtin_amdgcn_mfma_f32_16x16x32_f16(ah[kc], bh, a, 0,0,0);
      a = __builtin_amdgcn_mfma_f32_16x16x32_f16(ah[kc], bl, a, 0,0,0);
    }
    int n = nt*16 + l15;
    float bv = bias[n];
    #pragma unroll
    for (int r=0;r<4;r++){
      int t = t0 + mb + l4*4 + r;
      out[((size_t)b*TD + t)*INDIM + n] = a[r] + bv;
    }
  }
}

extern "C" void kernel_launch(void* const* d_in, const int* in_sizes, int n_in,
                              void* d_out, int out_size, void* d_ws, size_t ws_size,
                              hipStream_t stream) {
  const float* enc   = (const float*)d_in[0];
  const float* emb   = (const float*)d_in[1];
  const float* mel   = (const float*)d_in[2];
  const float* W_lin = (const float*)d_in[3];
  const float* b_lin = (const float*)d_in[4];
  const float* w0    = (const float*)d_in[5];
  const float* b0    = (const float*)d_in[6];
  const float* w1    = (const float*)d_in[7];
  const float* b1    = (const float*)d_in[8];
  const float* Wq    = (const float*)d_in[9];
  const float* bq    = (const float*)d_in[10];
  const float* Wp    = (const float*)d_in[11];
  const float* bp    = (const float*)d_in[12];
  float* out = (float*)d_out;

  const size_t NTOK = (size_t)BB*TD*DIM;           // 16.78M
  const size_t NE   = (size_t)BB*TE*DIM;           // 8.39M
  _Float16* Xb  = (_Float16*)d_ws;
  float*    H   = (float*)(Xb + NTOK);
  _Float16* Wf0 = (_Float16*)(H + NTOK);
  _Float16* Wf1 = Wf0 + (size_t)512*1280;
  _Float16* Wqh = Wf1 + (size_t)512*1280;
  _Float16* Wql = Wqh + 65536;
  _Float16* Wlh = Wql + 65536;                     // 256*96
  _Float16* Wll = Wlh + 24576;
  _Float16* Wph = Wll + 24576;                     // 80*256
  _Float16* Wpl = Wph + 20480;
  _Float16* Eh  = Xb;                              // after conv0 consumes Xb
  _Float16* EVt = Xb + NE;
  _Float16* Pb  = Xb;                              // after attn consumes Eh/EVt

  k_wprep    <<<2560, 256, 0, stream>>>(w0, Wf0);
  k_wprep    <<<2560, 256, 0, stream>>>(w1, Wf1);
  k_qwprep   <<<256,  256, 0, stream>>>(Wq, Wqh, Wql);
  k_lwprep   <<<96,   256, 0, stream>>>(W_lin, Wlh, Wll);
  k_pwprep   <<<80,   256, 0, stream>>>(Wp, Wph, Wpl);
  k_lin_mfma <<<1024, 256, 0, stream>>>(mel, Wlh, Wll, b_lin, Xb);
  k_conv_mfma<0,1><<<4096, 256, 0, stream>>>(Xb, Wf0, b0, H);
  k_eprep    <<<2048, 256, 0, stream>>>(enc, emb, Eh, EVt);
  k_attn     <<<1024, 256, 0, stream>>>(H, Wqh, Wql, bq, Eh, EVt);
  k_conv_mfma<1,0><<<4096, 256, 0, stream>>>(H, Wf1, b1, Pb);
  k_proj_mfma<<<1024, 256, 0, stream>>>(Pb, Wph, Wpl, bp, out);
}